// Round 23
// baseline (196.081 us; speedup 1.0000x reference)
//
#include <hip/hip_runtime.h>

typedef unsigned short u16;
typedef short bf16x8 __attribute__((ext_vector_type(8)));
typedef float f32x4 __attribute__((ext_vector_type(4)));
typedef float f32x16 __attribute__((ext_vector_type(16)));
typedef int i32x2 __attribute__((ext_vector_type(2)));
typedef unsigned int u32x4 __attribute__((ext_vector_type(4)));
typedef unsigned short u16x4 __attribute__((ext_vector_type(4)));
typedef unsigned short u16x8 __attribute__((ext_vector_type(8)));

#define S_LEN 2048
#define NHEAD 16
#define NKV 8
#define HD 128

__device__ __forceinline__ u16 f2bf(float f) {
  unsigned u = __builtin_bit_cast(unsigned, f);
  u = (u + 0x7FFFu + ((u >> 16) & 1u)) >> 16;
  return (u16)u;
}
__device__ __forceinline__ float bf2f(u16 h) {
  unsigned u = ((unsigned)h) << 16;
  return __builtin_bit_cast(float, u);
}

__device__ __forceinline__ void gl_lds16(const void* g, void* l) {
  __builtin_amdgcn_global_load_lds(
      (const __attribute__((address_space(1))) unsigned int*)g,
      (__attribute__((address_space(3))) unsigned int*)l, 16, 0, 0);
}

__device__ __forceinline__ unsigned cvtpk_bf16(float a, float b) {
  unsigned r;
  asm("v_cvt_pk_bf16_f32 %0, %1, %2" : "=v"(r) : "v"(a), "v"(b));
  return r;
}

// ==== fused prep: blocks 0-8191 convert x f32->bf16; 8192-11263 transpose
// ==== wq/wk/wv/wo f32 [K][N] -> bf16 [roff+n][2048] (vectorized stores)
__global__ __launch_bounds__(256) void prep(const float* __restrict__ x,
                                            u16* __restrict__ xo,
                                            const float* __restrict__ wq,
                                            const float* __restrict__ wk,
                                            const float* __restrict__ wv,
                                            const float* __restrict__ wo,
                                            u16* __restrict__ wcatT,
                                            u16* __restrict__ woT) {
  if (blockIdx.x < 8192) {
    int i = blockIdx.x * 256 + threadIdx.x;
    f32x4 v = *(const f32x4*)(x + (size_t)i * 4);
    u16x4 o;
#pragma unroll
    for (int j = 0; j < 4; ++j) o[j] = f2bf(v[j]);
    *(u16x4*)(xo + (size_t)i * 4) = o;
    return;
  }
  __shared__ float tile[64][65];
  int id = blockIdx.x - 8192;
  const float* in;
  u16* out;
  int N, roff, nx;
  if (id < 1024) {
    in = wq; out = wcatT; N = 2048; roff = 0; nx = 32;
  } else if (id < 1536) {
    in = wk; out = wcatT; N = 1024; roff = 2048; nx = 16; id -= 1024;
  } else if (id < 2048) {
    in = wv; out = wcatT; N = 1024; roff = 3072; nx = 16; id -= 1536;
  } else {
    in = wo; out = woT; N = 2048; roff = 0; nx = 32; id -= 2048;
  }
  int bx = id % nx;
  int by = id / nx;
  int k0 = by * 64, n0 = bx * 64;
  int tx = threadIdx.x & 63, ty = threadIdx.x >> 6;
#pragma unroll
  for (int p = 0; p < 16; ++p) {
    int r = p * 4 + ty;
    tile[r][tx] = in[(size_t)(k0 + r) * N + n0 + tx];
  }
  __syncthreads();
  // vectorized write: each thread stores u16x4 runs of k
  int nn = threadIdx.x >> 4;        // 0..15
  int k4 = (threadIdx.x & 15) * 4;  // 0..60
#pragma unroll
  for (int p = 0; p < 4; ++p) {
    int nrow = p * 16 + nn;
    u16x4 o;
#pragma unroll
    for (int j = 0; j < 4; ++j) o[j] = f2bf(tile[k4 + j][nrow]);
    *(u16x4*)(&out[(size_t)(roff + n0 + nrow) * 2048 + k0 + k4]) = o;
  }
}

// ===== QKV GEMM: 128x256 tile, BK=64, ring-3 (144KB), counted vmcnt, =====
// 2-D blocked XCD mapping (FETCH 175->69 MB measured); FUSED RoPE + V^T
// LDS bounce epilogue -> Vt [bkv][d][s].
__global__ __launch_bounds__(512, 1) void gemm_qkv(
    const u16* __restrict__ A, const u16* __restrict__ Bt, u16* __restrict__ Qo,
    u16* __restrict__ Ko, u16* __restrict__ Vt, const float* __restrict__ fc,
    const float* __restrict__ fs) {
  constexpr int K = 2048, NT = K / 64;  // 32 K-tiles
  constexpr int BSZ = (128 + 256) * 64;
  __shared__ __align__(16) u16 lds[3][BSZ];  // 144 KB

  const int t = threadIdx.x;
  const int l = t & 63, lh = l >> 4, ll = l & 15;
  const int w = t >> 6, wm = w >> 2, wn = w & 3;

  const int xcd = blockIdx.x & 7;
  const int c = blockIdx.x >> 3;
  const int tm = (xcd & 3) * 8 + (c & 7);    // 8 tm per XCD
  const int tn = (xcd >> 2) * 8 + (c >> 3);  // 8 tn per XCD

  const u16* Ab = A + (size_t)tm * 128 * K;
  const u16* Bb = Bt + (size_t)tn * 256 * K;

  const int sr = t >> 3;
  const int sc8 = ((t & 7) ^ (sr & 7)) * 8;

  f32x4 acc[4][4] = {};

  auto STAGE = [&](int tau) {
    const int kt = tau * 64;
    u16* buf = &lds[tau % 3][0];
#pragma unroll
    for (int cc = 0; cc < 2; ++cc)
      gl_lds16(Ab + (size_t)(cc * 64 + sr) * K + kt + sc8, buf + cc * 4096 + t * 8);
#pragma unroll
    for (int cc = 0; cc < 4; ++cc)
      gl_lds16(Bb + (size_t)(cc * 64 + sr) * K + kt + sc8,
               buf + 8192 + cc * 4096 + t * 8);
  };

  STAGE(0);
  STAGE(1);
  __builtin_amdgcn_s_waitcnt(0xF70 | 6);
  __builtin_amdgcn_s_barrier();
  asm volatile("" ::: "memory");

  for (int tt = 0; tt < NT; ++tt) {
    if (tt + 2 < NT) STAGE(tt + 2);
    const u16* bufA = &lds[tt % 3][0];
    const u16* bufB = bufA + 8192;
#pragma unroll
    for (int kk = 0; kk < 2; ++kk) {
      const int cb = ((kk * 4 + lh) ^ (ll & 7)) * 8;
      bf16x8 af[4], bv[4];
#pragma unroll
      for (int m = 0; m < 4; ++m)
        af[m] = *(const bf16x8*)(bufA + (wm * 64 + m * 16 + ll) * 64 + cb);
#pragma unroll
      for (int n = 0; n < 4; ++n)
        bv[n] = *(const bf16x8*)(bufB + (wn * 64 + n * 16 + ll) * 64 + cb);
      __builtin_amdgcn_s_setprio(1);
#pragma unroll
      for (int m = 0; m < 4; ++m)
#pragma unroll
        for (int n = 0; n < 4; ++n)
          acc[m][n] =
              __builtin_amdgcn_mfma_f32_16x16x32_bf16(af[m], bv[n], acc[m][n], 0, 0, 0);
      __builtin_amdgcn_s_setprio(0);
    }
    if (tt + 1 < NT) {
      if (tt + 2 < NT)
        __builtin_amdgcn_s_waitcnt(0xF70 | 6);
      else
        __builtin_amdgcn_s_waitcnt(0xF70);
      __builtin_amdgcn_s_barrier();
      asm volatile("" ::: "memory");
    }
  }

  if (tn < 12) {
    // ---- Q / K with fused RoPE (block-uniform branch) ----
    const float qsc = 0.12751744540368598f;  // log2(e)/sqrt(128)
#pragma unroll
    for (int m = 0; m < 4; ++m)
#pragma unroll
      for (int n = 0; n < 4; ++n)
#pragma unroll
        for (int j = 0; j < 4; ++j) {
          int row = tm * 128 + wm * 64 + m * 16 + lh * 4 + j;
          int col = tn * 256 + wn * 64 + n * 16 + ll;
          int s = row & (S_LEN - 1), d = col & 127;
          float v = acc[m][n][j];
          float p = __shfl_xor(v, 1);  // partner d^1, same row
          int d2 = d >> 1;
          float ccs = fc[s * 64 + d2], sn = fs[s * 64 + d2];
          float r = (d & 1) ? (p * sn + v * ccs) : (v * ccs - p * sn);
          int b = row >> 11;
          if (tn < 8) {
            Qo[(((size_t)b * NHEAD + (col >> 7)) * S_LEN + s) * HD + d] =
                f2bf(r * qsc);
          } else {
            Ko[(((size_t)b * NKV + ((col >> 7) & 7)) * S_LEN + s) * HD + d] =
                f2bf(r);
          }
        }
  } else {
    // ---- V: LDS-bounce transpose -> Vt [bkv][d][s] ----
    __syncthreads();  // ring buffers dead; safe to reuse
    u16* vt = (u16*)&lds[0][0];  // [256 dcol][136 s] padded
#pragma unroll
    for (int m = 0; m < 4; ++m)
#pragma unroll
      for (int n = 0; n < 4; ++n)
#pragma unroll
        for (int j = 0; j < 4; ++j) {
          int sl = wm * 64 + m * 16 + lh * 4 + j;   // 0..127
          int dcol = wn * 64 + n * 16 + ll;          // 0..255
          vt[dcol * 136 + sl] = f2bf(acc[m][n][j]);
        }
    __syncthreads();
    const int dcol = t >> 1, sh = (t & 1) * 64;
    const int d = dcol & 127;
    const int b = (tm * 128) >> 11;
    const int s0 = (tm * 128) & (S_LEN - 1);
    const int bkv = b * NKV + (tn - 12) * 2 + (dcol >> 7);
    u16* dst = Vt + ((size_t)bkv * HD + d) * S_LEN + s0 + sh;
    const u16* src = vt + dcol * 136 + sh;
#pragma unroll
    for (int cc = 0; cc < 8; ++cc)
      *(u16x8*)(dst + cc * 8) = *(const u16x8*)(src + cc * 8);
  }
}

// ===== wo GEMM: 128x256 tile, BK=32, ring-3 (72KB -> 2 blk/CU), counted =====
// vmcnt, 2-level XOR slot swizzle. wo has grid 256 = exactly 1 round: the
// 2nd resident block supplies the TLP that QKV gets from cross-round overlap.
__global__ __launch_bounds__(512, 2) void gemm_wo(const u16* __restrict__ A,
                                                  const u16* __restrict__ Bt,
                                                  float* __restrict__ Cf, int N) {
  constexpr int K = 2048, NT = K / 32;   // 64 K-tiles
  constexpr int BSZ = (128 + 256) * 32;  // 24 KB/slot
  __shared__ __align__(16) u16 lds[3][BSZ];

  const int t = threadIdx.x;
  const int l = t & 63, lh = l >> 4, ll = l & 15;
  const int w = t >> 6, wm = w >> 2, wn = w & 3;

  const int xcd = blockIdx.x & 7;
  const int c = blockIdx.x >> 3;
  const int tm = (xcd & 3) * 8 + (c & 7);    // 8 tm per XCD
  const int tn = (xcd >> 2) * 4 + (c >> 3);  // 4 tn per XCD

  const u16* Ab = A + (size_t)tm * 128 * K;
  const u16* Bb = Bt + (size_t)tn * 256 * K;

  const int sr = t >> 2;
  const int sc8 = ((t & 3) ^ (sr & 3) ^ ((sr >> 2) & 3)) * 8;

  f32x4 acc[4][4] = {};

  auto STAGE = [&](int tau) {
    const int kt = tau * 32;
    u16* buf = &lds[tau % 3][0];
    gl_lds16(Ab + (size_t)sr * K + kt + sc8, buf + t * 8);
#pragma unroll
    for (int cc = 0; cc < 2; ++cc)
      gl_lds16(Bb + (size_t)(cc * 128 + sr) * K + kt + sc8,
               buf + 4096 + cc * 4096 + t * 8);
  };

  STAGE(0);
  STAGE(1);
  __builtin_amdgcn_s_waitcnt(0xF70 | 3);  // tile 0 landed; tile 1 in flight
  __builtin_amdgcn_s_barrier();
  asm volatile("" ::: "memory");

  const int cb = (lh ^ (ll & 3) ^ ((ll >> 2) & 3)) * 8;
  for (int tt = 0; tt < NT; ++tt) {
    if (tt + 2 < NT) STAGE(tt + 2);
    const u16* bufA = &lds[tt % 3][0];
    const u16* bufB = bufA + 4096;
    bf16x8 af[4], bv[4];
#pragma unroll
    for (int m = 0; m < 4; ++m)
      af[m] = *(const bf16x8*)(bufA + (wm * 64 + m * 16 + ll) * 32 + cb);
#pragma unroll
    for (int n = 0; n < 4; ++n)
      bv[n] = *(const bf16x8*)(bufB + (wn * 64 + n * 16 + ll) * 32 + cb);
    __builtin_amdgcn_s_setprio(1);
#pragma unroll
    for (int m = 0; m < 4; ++m)
#pragma unroll
      for (int n = 0; n < 4; ++n)
        acc[m][n] =
            __builtin_amdgcn_mfma_f32_16x16x32_bf16(af[m], bv[n], acc[m][n], 0, 0, 0);
    __builtin_amdgcn_s_setprio(0);
    if (tt + 1 < NT) {
      if (tt + 2 < NT)
        __builtin_amdgcn_s_waitcnt(0xF70 | 3);
      else
        __builtin_amdgcn_s_waitcnt(0xF70);
      __builtin_amdgcn_s_barrier();
      asm volatile("" ::: "memory");
    }
  }

#pragma unroll
  for (int m = 0; m < 4; ++m)
#pragma unroll
    for (int n = 0; n < 4; ++n)
#pragma unroll
      for (int j = 0; j < 4; ++j) {
        int row = tm * 128 + wm * 64 + m * 16 + lh * 4 + j;
        int col = tn * 256 + wn * 64 + n * 16 + ll;
        Cf[(size_t)row * N + col] = acc[m][n][j];
      }
}

// ======= causal GQA flash attention: 32x32 MFMA, swapped QK^T, =======
// ======= in-register softmax (cvt_pk + permlane32_swap), no P-LDS =======
// Pairing: bids 0-255 carry qt 15..8 (first), 256-511 carry qt 0..7
// ascending -> per-CU qt pair sums to 15 -> uniform 34 KV-iters/CU.
// LDS = 64KB -> 2 blocks/CU; (256,2) keeps VGPR ~116.
__global__ __launch_bounds__(256, 2) void attn_fwd(const u16* __restrict__ Q,
                                                   const u16* __restrict__ Kh,
                                                   const u16* __restrict__ Vt,
                                                   u16* __restrict__ O) {
  __shared__ __align__(16) u16 KS[2][64 * 128];
  __shared__ __align__(16) u16 VS[2][128 * 64];

  const int t = threadIdx.x;
  const int l = t & 63, hi = l >> 5, ll = l & 31;
  const int wq = t >> 6;

  const int bid = blockIdx.x;
  const int qt = (bid < 256) ? (15 - (bid >> 5)) : ((bid - 256) >> 5);
  const int bh = bid & 31;
  const int b = bh >> 4, h = bh & 15;
  const int bkv = b * NKV + (h >> 1);

  const u16* Qb = Q + (size_t)bh * S_LEN * HD;
  const u16* Kb = Kh + (size_t)bkv * S_LEN * HD;
  const u16* Vb = Vt + (size_t)bkv * HD * S_LEN;

  const int q0w = qt * 128 + wq * 32;
  const int qg = q0w + ll;

  bf16x8 qf[8];
#pragma unroll
  for (int c = 0; c < 8; ++c)
    qf[c] = *(const bf16x8*)(Qb + (size_t)qg * HD + c * 16 + hi * 8);

  const int krow = t >> 4, kslot = t & 15;
  const int vrow = t >> 3, vslot = t & 7;
  u16x8 krg[4], vrg[4];

  auto loadKV = [&](int tile) {
    const int kv0 = tile * 64;
#pragma unroll
    for (int c = 0; c < 4; ++c) {
      int r = c * 16 + krow;
      int sg = (kslot & 8) | ((kslot & 7) ^ (r & 7));
      krg[c] = *(const u16x8*)(Kb + (size_t)(kv0 + r) * HD + sg * 8);
    }
#pragma unroll
    for (int c = 0; c < 4; ++c) {
      int d = c * 32 + vrow;
      int sg = vslot ^ (d & 7);
      vrg[c] = *(const u16x8*)(Vb + (size_t)d * S_LEN + kv0 + sg * 8);
    }
  };
  auto storeKV = [&](int bi) {
#pragma unroll
    for (int c = 0; c < 4; ++c)
      *(u16x8*)(&KS[bi][(c * 16 + krow) * 128 + kslot * 8]) = krg[c];
#pragma unroll
    for (int c = 0; c < 4; ++c)
      *(u16x8*)(&VS[bi][(c * 32 + vrow) * 64 + vslot * 8]) = vrg[c];
  };

  f32x16 accO[4] = {};
  float m = -1e30f, lsum = 0.f;

  const int nt = 2 * qt + 2;
  loadKV(0);
  storeKV(0);
  __syncthreads();

  for (int tt = 0; tt < nt; ++tt) {
    const int kv0 = tt * 64;
    const bool actn = (tt + 1 < nt);
    if (actn) loadKV(tt + 1);

    if (kv0 <= q0w + 31) {
      const u16* ks = &KS[tt & 1][0];
      const u16* vs = &VS[tt & 1][0];

      f32x16 st[2] = {};
      __builtin_amdgcn_s_setprio(1);
#pragma unroll
      for (int c = 0; c < 8; ++c) {
        int slot = 2 * c + hi;
        int eff = (slot & 8) | ((slot & 7) ^ (ll & 7));
        bf16x8 kf0 = *(const bf16x8*)(ks + (size_t)ll * 128 + eff * 8);
        st[0] = __builtin_amdgcn_mfma_f32_32x32x16_bf16(kf0, qf[c], st[0], 0, 0, 0);
        bf16x8 kf1 = *(const bf16x8*)(ks + (size_t)(32 + ll) * 128 + eff * 8);
        st[1] = __builtin_amdgcn_mfma_f32_32x32x16_bf16(kf1, qf[c], st[1], 0, 0, 0);
      }
      __builtin_amdgcn_s_setprio(0);

      if (kv0 + 63 > q0w) {
#pragma unroll
        for (int f = 0; f < 2; ++f)
#pragma unroll
          for (int r = 0; r < 16; ++r) {
            int kvg = kv0 + f * 32 + (r & 3) + 8 * (r >> 2) + 4 * hi;
            if (kvg > qg) st[f][r] = -1e30f;
          }
      }

      float a[16];
#pragma unroll
      for (int i = 0; i < 16; ++i) a[i] = fmaxf(st[0][i], st[1][i]);
#pragma unroll
      for (int s = 8; s >= 1; s >>= 1)
#pragma unroll
        for (int i = 0; i < 8; ++i)
          if (i < s) a[i] = fmaxf(a[i], a[i + s]);
      float pmax = fmaxf(a[0], __shfl_xor(a[0], 32));

      if (tt == 0) {
        m = pmax;
      } else if (!__all(pmax <= m + 8.0f)) {
        float mnew = fmaxf(m, pmax);
        float corr = __builtin_amdgcn_exp2f(m - mnew);
        m = mnew;
        lsum *= corr;
        int ci = __builtin_bit_cast(int, corr);
#pragma unroll
        for (int reg = 0; reg < 16; ++reg) {
          int row = (reg & 3) + 8 * (reg >> 2) + 4 * hi;
          float cq = __builtin_bit_cast(
              float, __builtin_amdgcn_ds_bpermute(row << 2, ci));
#pragma unroll
          for (int dblk = 0; dblk < 4; ++dblk) accO[dblk][reg] *= cq;
        }
      }

#pragma unroll
      for (int f = 0; f < 2; ++f)
#pragma unroll
        for (int r = 0; r < 16; ++r)
          st[f][r] = __builtin_amdgcn_exp2f(st[f][r] - m);
      float s1[16];
#pragma unroll
      for (int i = 0; i < 16; ++i) s1[i] = st[0][i] + st[1][i];
#pragma unroll
      for (int s = 8; s >= 1; s >>= 1)
#pragma unroll
        for (int i = 0; i < 8; ++i)
          if (i < s) s1[i] += s1[i + s];
      lsum += s1[0];

      unsigned pk[8][2];
#pragma unroll
      for (int bg = 0; bg < 8; ++bg)
#pragma unroll
        for (int ap = 0; ap < 2; ++ap)
          pk[bg][ap] = cvtpk_bf16(st[bg >> 2][(bg & 3) * 4 + 2 * ap],
                                  st[bg >> 2][(bg & 3) * 4 + 2 * ap + 1]);

      __builtin_amdgcn_s_setprio(1);
#pragma unroll
      for (int kc = 0; kc < 4; ++kc) {
        i32x2 sa = __builtin_amdgcn_permlane32_swap(
            (int)pk[2 * kc][0], (int)pk[2 * kc + 1][0], false, false);
        i32x2 sb = __builtin_amdgcn_permlane32_swap(
            (int)pk[2 * kc][1], (int)pk[2 * kc + 1][1], false, false);
        union {
          unsigned u[4];
          bf16x8 v;
        } pa;
        pa.u[0] = (unsigned)sa[0];
        pa.u[1] = (unsigned)sb[0];
        pa.u[2] = (unsigned)sa[1];
        pa.u[3] = (unsigned)sb[1];
        int eff = (2 * kc + hi) ^ (ll & 7);
#pragma unroll
        for (int dblk = 0; dblk < 4; ++dblk) {
          bf16x8 vf = *(const bf16x8*)(vs + (size_t)(dblk * 32 + ll) * 64 + eff * 8);
          accO[dblk] =
              __builtin_amdgcn_mfma_f32_32x32x16_bf16(pa.v, vf, accO[dblk], 0, 0, 0);
        }
      }
      __builtin_amdgcn_s_setprio(0);
    }

    __syncthreads();
    if (actn) storeKV((tt + 1) & 1);
    __syncthreads();
  }

  lsum += __shfl_xor(lsum, 32);
  float linv = 1.0f / lsum;
  int li = __builtin_bit_cast(int, linv);
  float inv[16];
#pragma unroll
  for (int reg = 0; reg < 16; ++reg) {
    int row = (reg & 3) + 8 * (reg >> 2) + 4 * hi;
    inv[reg] = __builtin_bit_cast(float, __builtin_amdgcn_ds_bpermute(row << 2, li));
  }
#pragma unroll
  for (int dblk = 0; dblk < 4; ++dblk)
#pragma unroll
    for (int reg = 0; reg < 16; ++reg) {
      int row = (reg & 3) + 8 * (reg >> 2) + 4 * hi;
      O[(size_t)(b * S_LEN + q0w + row) * 2048 + h * HD + dblk * 32 + ll] =
          f2bf(accO[dblk][reg] * inv[reg]);
    }
}

extern "C" void kernel_launch(void* const* d_in, const int* in_sizes, int n_in,
                              void* d_out, int out_size, void* d_ws, size_t ws_size,
                              hipStream_t stream) {
  (void)in_sizes;
  (void)n_in;
  (void)out_size;
  (void)ws_size;
  const float* x = (const float*)d_in[0];
  const float* fc = (const float*)d_in[1];
  const float* fs = (const float*)d_in[2];
  const float* wq = (const float*)d_in[3];
  const float* wk = (const float*)d_in[4];
  const float* wv = (const float*)d_in[5];
  const float* wo = (const float*)d_in[6];
  float* out = (float*)d_out;

  char* ws = (char*)d_ws;
  u16* wcatT = (u16*)ws;             // [4096][2048] bf16  16.78 MB
  u16* woT = (u16*)(ws + 16777216);  // [2048][2048]        8.39 MB
  u16* xo = (u16*)(ws + 25165824);   // x_bf16 then O      16.78 MB
  u16* qb = (u16*)(ws + 41943040);   // [32][2048][128]    16.78 MB
  u16* kb = (u16*)(ws + 58720256);   // [16][2048][128]     8.39 MB
  u16* vtb = (u16*)(ws + 67108864);  // Vt [16][128][2048]  8.39 MB
  // total 75,497,472 bytes

  prep<<<11264, 256, 0, stream>>>(x, xo, wq, wk, wv, wo, wcatT, woT);

  gemm_qkv<<<512, 512, 0, stream>>>(xo, wcatT, qb, kb, vtb, fc, fs);
  attn_fwd<<<512, 256, 0, stream>>>(qb, kb, vtb, xo);
  gemm_wo<<<256, 512, 0, stream>>>(xo, woT, out, 2048);
}

// Round 24
// 190.923 us; speedup vs baseline: 1.0270x; 1.0270x over previous
//
#include <hip/hip_runtime.h>

typedef unsigned short u16;
typedef short bf16x8 __attribute__((ext_vector_type(8)));
typedef float f32x4 __attribute__((ext_vector_type(4)));
typedef float f32x16 __attribute__((ext_vector_type(16)));
typedef int i32x2 __attribute__((ext_vector_type(2)));
typedef unsigned int u32x4 __attribute__((ext_vector_type(4)));
typedef unsigned short u16x4 __attribute__((ext_vector_type(4)));
typedef unsigned short u16x8 __attribute__((ext_vector_type(8)));

#define S_LEN 2048
#define NHEAD 16
#define NKV 8
#define HD 128

__device__ __forceinline__ u16 f2bf(float f) {
  unsigned u = __builtin_bit_cast(unsigned, f);
  u = (u + 0x7FFFu + ((u >> 16) & 1u)) >> 16;
  return (u16)u;
}
__device__ __forceinline__ float bf2f(u16 h) {
  unsigned u = ((unsigned)h) << 16;
  return __builtin_bit_cast(float, u);
}

__device__ __forceinline__ void gl_lds16(const void* g, void* l) {
  __builtin_amdgcn_global_load_lds(
      (const __attribute__((address_space(1))) unsigned int*)g,
      (__attribute__((address_space(3))) unsigned int*)l, 16, 0, 0);
}

__device__ __forceinline__ unsigned cvtpk_bf16(float a, float b) {
  unsigned r;
  asm("v_cvt_pk_bf16_f32 %0, %1, %2" : "=v"(r) : "v"(a), "v"(b));
  return r;
}

// ==== fused prep: blocks 0-8191 convert x f32->bf16; 8192-11263 transpose
// ==== wq/wk/wv/wo f32 [K][N] -> bf16 [roff+n][2048] (vectorized stores)
__global__ __launch_bounds__(256) void prep(const float* __restrict__ x,
                                            u16* __restrict__ xo,
                                            const float* __restrict__ wq,
                                            const float* __restrict__ wk,
                                            const float* __restrict__ wv,
                                            const float* __restrict__ wo,
                                            u16* __restrict__ wcatT,
                                            u16* __restrict__ woT) {
  if (blockIdx.x < 8192) {
    int i = blockIdx.x * 256 + threadIdx.x;
    f32x4 v = *(const f32x4*)(x + (size_t)i * 4);
    u16x4 o;
#pragma unroll
    for (int j = 0; j < 4; ++j) o[j] = f2bf(v[j]);
    *(u16x4*)(xo + (size_t)i * 4) = o;
    return;
  }
  __shared__ float tile[64][65];
  int id = blockIdx.x - 8192;
  const float* in;
  u16* out;
  int N, roff, nx;
  if (id < 1024) {
    in = wq; out = wcatT; N = 2048; roff = 0; nx = 32;
  } else if (id < 1536) {
    in = wk; out = wcatT; N = 1024; roff = 2048; nx = 16; id -= 1024;
  } else if (id < 2048) {
    in = wv; out = wcatT; N = 1024; roff = 3072; nx = 16; id -= 1536;
  } else {
    in = wo; out = woT; N = 2048; roff = 0; nx = 32; id -= 2048;
  }
  int bx = id % nx;
  int by = id / nx;
  int k0 = by * 64, n0 = bx * 64;
  int tx = threadIdx.x & 63, ty = threadIdx.x >> 6;
#pragma unroll
  for (int p = 0; p < 16; ++p) {
    int r = p * 4 + ty;
    tile[r][tx] = in[(size_t)(k0 + r) * N + n0 + tx];
  }
  __syncthreads();
  // vectorized write: each thread stores u16x4 runs of k
  int nn = threadIdx.x >> 4;        // 0..15
  int k4 = (threadIdx.x & 15) * 4;  // 0..60
#pragma unroll
  for (int p = 0; p < 4; ++p) {
    int nrow = p * 16 + nn;
    u16x4 o;
#pragma unroll
    for (int j = 0; j < 4; ++j) o[j] = f2bf(tile[k4 + j][nrow]);
    *(u16x4*)(&out[(size_t)(roff + n0 + nrow) * 2048 + k0 + k4]) = o;
  }
}

// ===== ring-3 deep-pipelined GEMM: 128x256 tile, BK=64, counted vmcnt =====
// 2-D blocked XCD mapping: each XCD owns a square sub-grid so its 32
// concurrent CUs keep A+B panels ~L2-resident (FETCH 175->69 MB measured).
// EPI 1: QKV with FUSED RoPE + V^T LDS bounce -> Vt [bkv][d][s].
// EPI 0: wo, direct f32 C store (full K).
template <int EPI>
__global__ __launch_bounds__(512, 1) void gemm3r(
    const u16* __restrict__ A, const u16* __restrict__ Bt, float* __restrict__ Cf,
    u16* __restrict__ Qo, u16* __restrict__ Ko, u16* __restrict__ Vt,
    const float* __restrict__ fc, const float* __restrict__ fs, int N, int ntn) {
  constexpr int K = 2048, NT = K / 64;  // 32 K-tiles
  constexpr int BSZ = (128 + 256) * 64;
  __shared__ __align__(16) u16 lds[3][BSZ];  // 144 KB

  const int t = threadIdx.x;
  const int l = t & 63, lh = l >> 4, ll = l & 15;
  const int w = t >> 6, wm = w >> 2, wn = w & 3;

  // 2-D blocked XCD mapping (grid: EPI1 512 = 32tm x 16tn; EPI0 256 = 32tm x 8tn)
  const int xcd = blockIdx.x & 7;
  const int c = blockIdx.x >> 3;
  int tm, tn;
  if constexpr (EPI == 1) {
    tm = (xcd & 3) * 8 + (c & 7);        // 8 tm per XCD
    tn = (xcd >> 2) * 8 + (c >> 3);      // 8 tn per XCD
  } else {
    tm = (xcd & 3) * 8 + (c & 7);        // 8 tm per XCD
    tn = (xcd >> 2) * 4 + (c >> 3);      // 4 tn per XCD
  }
  (void)ntn;

  const u16* Ab = A + (size_t)tm * 128 * K;
  const u16* Bb = Bt + (size_t)tn * 256 * K;

  const int sr = t >> 3;
  const int sc8 = ((t & 7) ^ (sr & 7)) * 8;

  f32x4 acc[4][4] = {};

  auto STAGE = [&](int tau) {
    const int kt = tau * 64;
    u16* buf = &lds[tau % 3][0];
#pragma unroll
    for (int cc = 0; cc < 2; ++cc)
      gl_lds16(Ab + (size_t)(cc * 64 + sr) * K + kt + sc8, buf + cc * 4096 + t * 8);
#pragma unroll
    for (int cc = 0; cc < 4; ++cc)
      gl_lds16(Bb + (size_t)(cc * 64 + sr) * K + kt + sc8,
               buf + 8192 + cc * 4096 + t * 8);
  };

  STAGE(0);
  STAGE(1);
  __builtin_amdgcn_s_waitcnt(0xF70 | 6);
  __builtin_amdgcn_s_barrier();
  asm volatile("" ::: "memory");

  for (int tt = 0; tt < NT; ++tt) {
    if (tt + 2 < NT) STAGE(tt + 2);
    const u16* bufA = &lds[tt % 3][0];
    const u16* bufB = bufA + 8192;
#pragma unroll
    for (int kk = 0; kk < 2; ++kk) {
      const int cb = ((kk * 4 + lh) ^ (ll & 7)) * 8;
      bf16x8 af[4], bv[4];
#pragma unroll
      for (int m = 0; m < 4; ++m)
        af[m] = *(const bf16x8*)(bufA + (wm * 64 + m * 16 + ll) * 64 + cb);
#pragma unroll
      for (int n = 0; n < 4; ++n)
        bv[n] = *(const bf16x8*)(bufB + (wn * 64 + n * 16 + ll) * 64 + cb);
      __builtin_amdgcn_s_setprio(1);
#pragma unroll
      for (int m = 0; m < 4; ++m)
#pragma unroll
        for (int n = 0; n < 4; ++n)
          acc[m][n] =
              __builtin_amdgcn_mfma_f32_16x16x32_bf16(af[m], bv[n], acc[m][n], 0, 0, 0);
      __builtin_amdgcn_s_setprio(0);
    }
    if (tt + 1 < NT) {
      if (tt + 2 < NT)
        __builtin_amdgcn_s_waitcnt(0xF70 | 6);
      else
        __builtin_amdgcn_s_waitcnt(0xF70);
      __builtin_amdgcn_s_barrier();
      asm volatile("" ::: "memory");
    }
  }

  if constexpr (EPI == 0) {
#pragma unroll
    for (int m = 0; m < 4; ++m)
#pragma unroll
      for (int n = 0; n < 4; ++n)
#pragma unroll
        for (int j = 0; j < 4; ++j) {
          int row = tm * 128 + wm * 64 + m * 16 + lh * 4 + j;
          int col = tn * 256 + wn * 64 + n * 16 + ll;
          Cf[(size_t)row * N + col] = acc[m][n][j];
        }
  } else {
    if (tn < 12) {
      // ---- Q / K with fused RoPE (block-uniform branch) ----
      const float qsc = 0.12751744540368598f;  // log2(e)/sqrt(128)
#pragma unroll
      for (int m = 0; m < 4; ++m)
#pragma unroll
        for (int n = 0; n < 4; ++n)
#pragma unroll
          for (int j = 0; j < 4; ++j) {
            int row = tm * 128 + wm * 64 + m * 16 + lh * 4 + j;
            int col = tn * 256 + wn * 64 + n * 16 + ll;
            int s = row & (S_LEN - 1), d = col & 127;
            float v = acc[m][n][j];
            float p = __shfl_xor(v, 1);  // partner d^1, same row
            int d2 = d >> 1;
            float ccs = fc[s * 64 + d2], sn = fs[s * 64 + d2];
            float r = (d & 1) ? (p * sn + v * ccs) : (v * ccs - p * sn);
            int b = row >> 11;
            if (tn < 8) {
              Qo[(((size_t)b * NHEAD + (col >> 7)) * S_LEN + s) * HD + d] =
                  f2bf(r * qsc);
            } else {
              Ko[(((size_t)b * NKV + ((col >> 7) & 7)) * S_LEN + s) * HD + d] =
                  f2bf(r);
            }
          }
    } else {
      // ---- V: LDS-bounce transpose -> Vt [bkv][d][s] ----
      __syncthreads();  // ring buffers dead; safe to reuse
      u16* vt = (u16*)&lds[0][0];  // [256 dcol][136 s] padded
#pragma unroll
      for (int m = 0; m < 4; ++m)
#pragma unroll
        for (int n = 0; n < 4; ++n)
#pragma unroll
          for (int j = 0; j < 4; ++j) {
            int sl = wm * 64 + m * 16 + lh * 4 + j;   // 0..127
            int dcol = wn * 64 + n * 16 + ll;          // 0..255
            vt[dcol * 136 + sl] = f2bf(acc[m][n][j]);
          }
      __syncthreads();
      const int dcol = t >> 1, sh = (t & 1) * 64;
      const int d = dcol & 127;
      const int b = (tm * 128) >> 11;
      const int s0 = (tm * 128) & (S_LEN - 1);
      const int bkv = b * NKV + (tn - 12) * 2 + (dcol >> 7);
      u16* dst = Vt + ((size_t)bkv * HD + d) * S_LEN + s0 + sh;
      const u16* src = vt + dcol * 136 + sh;
#pragma unroll
      for (int cc = 0; cc < 8; ++cc)
        *(u16x8*)(dst + cc * 8) = *(const u16x8*)(src + cc * 8);
    }
  }
}

// ======= causal GQA flash attention: 32x32 MFMA, swapped QK^T, =======
// ======= in-register softmax (cvt_pk + permlane32_swap), no P-LDS =======
// Pairing: bids 0-255 carry qt 15..8 (first), 256-511 carry qt 0..7
// ascending -> per-CU qt pair sums to 15 -> uniform 34 KV-iters/CU.
// NOTE: LDS = 64KB -> 2 blocks/CU; (256,2) keeps VGPR ~116 (R21's (256,3)
// ballooned VGPR to 164 and halved occupancy — regression).
__global__ __launch_bounds__(256, 2) void attn_fwd(const u16* __restrict__ Q,
                                                   const u16* __restrict__ Kh,
                                                   const u16* __restrict__ Vt,
                                                   u16* __restrict__ O) {
  __shared__ __align__(16) u16 KS[2][64 * 128];
  __shared__ __align__(16) u16 VS[2][128 * 64];

  const int t = threadIdx.x;
  const int l = t & 63, hi = l >> 5, ll = l & 31;
  const int wq = t >> 6;

  const int bid = blockIdx.x;
  const int qt = (bid < 256) ? (15 - (bid >> 5)) : ((bid - 256) >> 5);
  const int bh = bid & 31;
  const int b = bh >> 4, h = bh & 15;
  const int bkv = b * NKV + (h >> 1);

  const u16* Qb = Q + (size_t)bh * S_LEN * HD;
  const u16* Kb = Kh + (size_t)bkv * S_LEN * HD;
  const u16* Vb = Vt + (size_t)bkv * HD * S_LEN;

  const int q0w = qt * 128 + wq * 32;
  const int qg = q0w + ll;

  bf16x8 qf[8];
#pragma unroll
  for (int c = 0; c < 8; ++c)
    qf[c] = *(const bf16x8*)(Qb + (size_t)qg * HD + c * 16 + hi * 8);

  const int krow = t >> 4, kslot = t & 15;
  const int vrow = t >> 3, vslot = t & 7;
  u16x8 krg[4], vrg[4];

  auto loadKV = [&](int tile) {
    const int kv0 = tile * 64;
#pragma unroll
    for (int c = 0; c < 4; ++c) {
      int r = c * 16 + krow;
      int sg = (kslot & 8) | ((kslot & 7) ^ (r & 7));
      krg[c] = *(const u16x8*)(Kb + (size_t)(kv0 + r) * HD + sg * 8);
    }
#pragma unroll
    for (int c = 0; c < 4; ++c) {
      int d = c * 32 + vrow;
      int sg = vslot ^ (d & 7);
      vrg[c] = *(const u16x8*)(Vb + (size_t)d * S_LEN + kv0 + sg * 8);
    }
  };
  auto storeKV = [&](int bi) {
#pragma unroll
    for (int c = 0; c < 4; ++c)
      *(u16x8*)(&KS[bi][(c * 16 + krow) * 128 + kslot * 8]) = krg[c];
#pragma unroll
    for (int c = 0; c < 4; ++c)
      *(u16x8*)(&VS[bi][(c * 32 + vrow) * 64 + vslot * 8]) = vrg[c];
  };

  f32x16 accO[4] = {};
  float m = -1e30f, lsum = 0.f;

  const int nt = 2 * qt + 2;
  loadKV(0);
  storeKV(0);
  __syncthreads();

  for (int tt = 0; tt < nt; ++tt) {
    const int kv0 = tt * 64;
    const bool actn = (tt + 1 < nt);
    if (actn) loadKV(tt + 1);

    if (kv0 <= q0w + 31) {
      const u16* ks = &KS[tt & 1][0];
      const u16* vs = &VS[tt & 1][0];

      f32x16 st[2] = {};
      __builtin_amdgcn_s_setprio(1);
#pragma unroll
      for (int c = 0; c < 8; ++c) {
        int slot = 2 * c + hi;
        int eff = (slot & 8) | ((slot & 7) ^ (ll & 7));
        bf16x8 kf0 = *(const bf16x8*)(ks + (size_t)ll * 128 + eff * 8);
        st[0] = __builtin_amdgcn_mfma_f32_32x32x16_bf16(kf0, qf[c], st[0], 0, 0, 0);
        bf16x8 kf1 = *(const bf16x8*)(ks + (size_t)(32 + ll) * 128 + eff * 8);
        st[1] = __builtin_amdgcn_mfma_f32_32x32x16_bf16(kf1, qf[c], st[1], 0, 0, 0);
      }
      __builtin_amdgcn_s_setprio(0);

      if (kv0 + 63 > q0w) {
#pragma unroll
        for (int f = 0; f < 2; ++f)
#pragma unroll
          for (int r = 0; r < 16; ++r) {
            int kvg = kv0 + f * 32 + (r & 3) + 8 * (r >> 2) + 4 * hi;
            if (kvg > qg) st[f][r] = -1e30f;
          }
      }

      float a[16];
#pragma unroll
      for (int i = 0; i < 16; ++i) a[i] = fmaxf(st[0][i], st[1][i]);
#pragma unroll
      for (int s = 8; s >= 1; s >>= 1)
#pragma unroll
        for (int i = 0; i < 8; ++i)
          if (i < s) a[i] = fmaxf(a[i], a[i + s]);
      float pmax = fmaxf(a[0], __shfl_xor(a[0], 32));

      if (tt == 0) {
        m = pmax;
      } else if (!__all(pmax <= m + 8.0f)) {
        float mnew = fmaxf(m, pmax);
        float corr = __builtin_amdgcn_exp2f(m - mnew);
        m = mnew;
        lsum *= corr;
        int ci = __builtin_bit_cast(int, corr);
#pragma unroll
        for (int reg = 0; reg < 16; ++reg) {
          int row = (reg & 3) + 8 * (reg >> 2) + 4 * hi;
          float cq = __builtin_bit_cast(
              float, __builtin_amdgcn_ds_bpermute(row << 2, ci));
#pragma unroll
          for (int dblk = 0; dblk < 4; ++dblk) accO[dblk][reg] *= cq;
        }
      }

#pragma unroll
      for (int f = 0; f < 2; ++f)
#pragma unroll
        for (int r = 0; r < 16; ++r)
          st[f][r] = __builtin_amdgcn_exp2f(st[f][r] - m);
      float s1[16];
#pragma unroll
      for (int i = 0; i < 16; ++i) s1[i] = st[0][i] + st[1][i];
#pragma unroll
      for (int s = 8; s >= 1; s >>= 1)
#pragma unroll
        for (int i = 0; i < 8; ++i)
          if (i < s) s1[i] += s1[i + s];
      lsum += s1[0];

      unsigned pk[8][2];
#pragma unroll
      for (int bg = 0; bg < 8; ++bg)
#pragma unroll
        for (int ap = 0; ap < 2; ++ap)
          pk[bg][ap] = cvtpk_bf16(st[bg >> 2][(bg & 3) * 4 + 2 * ap],
                                  st[bg >> 2][(bg & 3) * 4 + 2 * ap + 1]);

      __builtin_amdgcn_s_setprio(1);
#pragma unroll
      for (int kc = 0; kc < 4; ++kc) {
        i32x2 sa = __builtin_amdgcn_permlane32_swap(
            (int)pk[2 * kc][0], (int)pk[2 * kc + 1][0], false, false);
        i32x2 sb = __builtin_amdgcn_permlane32_swap(
            (int)pk[2 * kc][1], (int)pk[2 * kc + 1][1], false, false);
        union {
          unsigned u[4];
          bf16x8 v;
        } pa;
        pa.u[0] = (unsigned)sa[0];
        pa.u[1] = (unsigned)sb[0];
        pa.u[2] = (unsigned)sa[1];
        pa.u[3] = (unsigned)sb[1];
        int eff = (2 * kc + hi) ^ (ll & 7);
#pragma unroll
        for (int dblk = 0; dblk < 4; ++dblk) {
          bf16x8 vf = *(const bf16x8*)(vs + (size_t)(dblk * 32 + ll) * 64 + eff * 8);
          accO[dblk] =
              __builtin_amdgcn_mfma_f32_32x32x16_bf16(pa.v, vf, accO[dblk], 0, 0, 0);
        }
      }
      __builtin_amdgcn_s_setprio(0);
    }

    __syncthreads();
    if (actn) storeKV((tt + 1) & 1);
    __syncthreads();
  }

  lsum += __shfl_xor(lsum, 32);
  float linv = 1.0f / lsum;
  int li = __builtin_bit_cast(int, linv);
  float inv[16];
#pragma unroll
  for (int reg = 0; reg < 16; ++reg) {
    int row = (reg & 3) + 8 * (reg >> 2) + 4 * hi;
    inv[reg] = __builtin_bit_cast(float, __builtin_amdgcn_ds_bpermute(row << 2, li));
  }
#pragma unroll
  for (int dblk = 0; dblk < 4; ++dblk)
#pragma unroll
    for (int reg = 0; reg < 16; ++reg) {
      int row = (reg & 3) + 8 * (reg >> 2) + 4 * hi;
      O[(size_t)(b * S_LEN + q0w + row) * 2048 + h * HD + dblk * 32 + ll] =
          f2bf(accO[dblk][reg] * inv[reg]);
    }
}

extern "C" void kernel_launch(void* const* d_in, const int* in_sizes, int n_in,
                              void* d_out, int out_size, void* d_ws, size_t ws_size,
                              hipStream_t stream) {
  (void)in_sizes;
  (void)n_in;
  (void)out_size;
  (void)ws_size;
  const float* x = (const float*)d_in[0];
  const float* fc = (const float*)d_in[1];
  const float* fs = (const float*)d_in[2];
  const float* wq = (const float*)d_in[3];
  const float* wk = (const float*)d_in[4];
  const float* wv = (const float*)d_in[5];
  const float* wo = (const float*)d_in[6];
  float* out = (float*)d_out;

  char* ws = (char*)d_ws;
  u16* wcatT = (u16*)ws;             // [4096][2048] bf16  16.78 MB
  u16* woT = (u16*)(ws + 16777216);  // [2048][2048]        8.39 MB
  u16* xo = (u16*)(ws + 25165824);   // x_bf16 then O      16.78 MB
  u16* qb = (u16*)(ws + 41943040);   // [32][2048][128]    16.78 MB
  u16* kb = (u16*)(ws + 58720256);   // [16][2048][128]     8.39 MB
  u16* vtb = (u16*)(ws + 67108864);  // Vt [16][128][2048]  8.39 MB
  // total 75,497,472 bytes

  prep<<<11264, 256, 0, stream>>>(x, xo, wq, wk, wv, wo, wcatT, woT);

  gemm3r<1><<<512, 512, 0, stream>>>(xo, wcatT, nullptr, qb, kb, vtb, fc, fs, 4096,
                                     16);
  attn_fwd<<<512, 256, 0, stream>>>(qb, kb, vtb, xo);
  gemm3r<0><<<256, 512, 0, stream>>>(xo, woT, out, nullptr, nullptr, nullptr, nullptr,
                                     nullptr, 2048, 8);
}